// Round 9
// baseline (491.503 us; speedup 1.0000x reference)
//
#include <hip/hip_runtime.h>
#include <hip/hip_fp16.h>

#define HW 36864      // 192*192
#define IMGS 128      // B*C

typedef _Float16 h16;
typedef _Float16 v8h __attribute__((ext_vector_type(8)));
typedef _Float16 v4h __attribute__((ext_vector_type(4)));
typedef float v4f __attribute__((ext_vector_type(4)));

static __device__ __forceinline__ int imax(int a, int b) { return a > b ? a : b; }
static __device__ __forceinline__ int imin(int a, int b) { return a < b ? a : b; }

__device__ __constant__ float LIFT_C[6] = {
  -0.5f, 0.25f,                                            // bior53
  -1.586134342f, -0.05298011854f, 0.8829110762f, 0.4435068522f  // bior97
};
__device__ __constant__ int FIR_L[4]   = {8, 12, 12, 30};
__device__ __constant__ int FIR_PA[4]  = {2, 4, 4, 13};
__device__ __constant__ int FIR_OFF[4] = {0, 8, 20, 32};

// raw (unnormalized) FIR lowpass filters concatenated: db4(8) db6(12) sym6(12) coif5(30)
__device__ constexpr float FIRC[62] = {
  -0.0105974017850021f, 0.0328830116668852f, 0.0308413818355607f, -0.1870348117188811f,
  -0.0279837694169839f, 0.6308807679295904f, 0.7148465705529155f, 0.2303778133088964f,
  0.00107730108499558f, -0.00477725751101065f, -0.0005538422009938f, 0.03158203931748603f,
  0.02752286553030533f, -0.0975016055873225f, -0.12976686756709563f, 0.22626469396544f,
  0.3152503517092432f, -0.7511339080210959f, 0.4946238903984534f, 0.1115407433501095f,
  -0.007800708325034148f, 0.001767711864242804f, 0.04472490177066578f, -0.02106029251230056f,
  -0.0726375227866f, 0.3379294217282401f, 0.787641141030194f, 0.4910559419267466f,
  -0.048311742585632f, -0.1179901111484105f, 0.00349071208421747f, 0.01540410932702737f,
  -3.459977283621256e-05f, -7.098330313814114e-05f, 0.0004662169601128863f, 0.001117518770890601f,
  -0.002574517688750223f, -0.00900797613666158f, 0.015880544863615904f, 0.03455502757306163f,
  -0.08230192710688598f, -0.07179982161931202f, 0.42848347637761874f, 0.7937772226256206f,
  0.4051769024096169f, -0.06112339000267287f, -0.06577191128185562f, 0.023452696141836267f,
  0.007782596427325418f, -0.003793512864491014f, -0.0002606761356811993f, 0.000107502882505652f,
  1.10319778524429e-05f, -5.520763127949e-06f, -1.0682196848076e-06f, 5.236425333584e-07f,
  1.125098976034e-07f, -5.417490769329e-08f, -8.8631e-09f, 4.2921e-09f, 6.7e-10f, -3.2e-10f,
};

// ---------------- gate: 1x1 conv -> relu -> 1x1 conv -> softmax -> renorm (fp16 out) ----------------
__global__ __launch_bounds__(256) void k_gate(
    const float* __restrict__ x, const float* __restrict__ w1, const float* __restrict__ b1,
    const float* __restrict__ w2, const float* __restrict__ b2, h16* __restrict__ gate)
{
  __shared__ float w1s[256], b1s[8], w2s[48], b2s[6];
  int tid = threadIdx.x;
  w1s[tid] = w1[tid];
  if (tid < 8)  b1s[tid] = b1[tid];
  if (tid < 48) w2s[tid] = w2[tid];
  if (tid < 6)  b2s[tid] = b2[tid];
  __syncthreads();
  int px = blockIdx.x * 256 + tid;        // exactly 4*HW threads
  int b = px / HW, p = px - b * HW;
  const float* xb = x + (size_t)b * 32 * HW + p;
  float xv[32];
#pragma unroll
  for (int c = 0; c < 32; ++c) xv[c] = xb[(size_t)c * HW];
  float hb[8];
#pragma unroll
  for (int j = 0; j < 8; ++j) {
    float s = b1s[j];
#pragma unroll
    for (int c = 0; c < 32; ++c) s += w1s[j * 32 + c] * xv[c];
    hb[j] = fmaxf(s, 0.f);
  }
  float e[6], mx = -1e30f;
#pragma unroll
  for (int k = 0; k < 6; ++k) {
    float s = b2s[k];
#pragma unroll
    for (int j = 0; j < 8; ++j) s += w2s[k * 8 + j] * hb[j];
    e[k] = s; mx = fmaxf(mx, s);
  }
  float se = 0.f;
#pragma unroll
  for (int k = 0; k < 6; ++k) { e[k] = expf(e[k] - mx); se += e[k]; }
  float inv = 1.f / se, s2 = 0.f;
#pragma unroll
  for (int k = 0; k < 6; ++k) { e[k] *= inv; s2 += e[k]; }
  float inv2 = 1.f / (s2 + 1e-12f);
  h16* gp = gate + (size_t)b * 6 * HW + p;
#pragma unroll
  for (int k = 0; k < 6; ++k) gp[(size_t)k * HW] = (h16)(e[k] * inv2);
}

// ---------------- build the 12 operator matrices (fp16, 192x192 row-major [out][in]) ----------------
__global__ __launch_bounds__(64) void k_build(
    h16* __restrict__ Kall, const float* __restrict__ s53A, const float* __restrict__ s53D,
    const float* __restrict__ s97A, const float* __restrict__ s97D)
{
  const int col = blockIdx.x;      // 0..191 (input index)
  const int mat = blockIdx.y;      // 0..11
  const int cand = mat >> 1, side = mat & 1;
  const int tid = threadIdx.x;
  h16* out = Kall + (size_t)mat * HW;
  if (cand < 4) {
    const int Lf = FIR_L[cand], PA = FIR_PA[cand], OFF = FIR_OFF[cand];
    float ss = 0.f;
    for (int j = 0; j < Lf; ++j) ss += FIRC[OFF + j] * FIRC[OFF + j];
    const float invn = 1.f / (sqrtf(ss) + 1e-12f);
    for (int i = tid; i < 192; i += 64) {
      const int d = (i < 96) ? 1 : 2;
      const int q0 = i - d;
      const int i0 = imax(q0, 0), i1 = imin(q0 + 1, 189);
      const float tt = (float)d - (float)(2 * i + 1) * (1.f / 192.f);
      float c0 = 0.f, c1 = 0.f;
      for (int j = 0; j < Lf; ++j) {
        float fj = side ? (((j & 1) ? -1.f : 1.f) * FIRC[OFF + Lf - 1 - j]) : FIRC[OFF + j];
        fj *= invn;
        int r0 = i0 + j - PA; r0 = r0 < 0 ? -r0 : (r0 > 191 ? 382 - r0 : r0);
        int r1 = i1 + j - PA; r1 = r1 < 0 ? -r1 : (r1 > 191 ? 382 - r1 : r1);
        if (r0 == col) c0 += fj;
        if (r1 == col) c1 += fj;
      }
      out[(size_t)i * 192 + col] = (h16)((1.f - tt) * c0 + tt * c1);
    }
  } else {
    __shared__ float yb[192];
    __shared__ float sb[96];
    yb[tid] = 0.f; yb[tid + 64] = 0.f; yb[tid + 128] = 0.f;
    __syncthreads();
    if (tid == 0) yb[col] = 1.f;
    __syncthreads();
    const int c97 = (cand == 5);
    const int base = c97 ? 2 : 0, ns = c97 ? 4 : 2;
    for (int s = 0; s < ns; ++s) {
      const float cf = LIFT_C[base + s] * 0.5f;
      for (int j = tid; j < 96; j += 64) {
        int jm = (j == 0) ? 1 : j - 1, jp = (j == 95) ? 94 : j + 1;
        if ((s & 1) == 0) yb[2 * j + 1] += cf * (yb[2 * jm] + yb[2 * jp]);
        else              yb[2 * j]     += cf * (yb[2 * jm + 1] + yb[2 * jp + 1]);
      }
      __syncthreads();
    }
    const float sA = c97 ? s97A[0] : s53A[0];
    const float sD = c97 ? s97D[0] : s53D[0];
    for (int u = tid; u < 96; u += 64)
      sb[u] = side ? sD * yb[2 * u + 1] : sA * yb[2 * u];
    __syncthreads();
    for (int i = tid; i < 192; i += 64) {
      const int u0 = (i >> 1) + (i & 1) - 1;
      const float tt = (i & 1) ? 0.25f : 0.75f;
      const int a0 = imax(u0, 0), a1 = imin(u0 + 1, 95);
      out[(size_t)i * 192 + col] = (h16)((1.f - tt) * sb[a0] + tt * sb[a1]);
    }
  }
}

// ---------------- pass W (R3-proven, byte-identical to the 305.8us run) ----------------
// grid (2 half x 4 plane-groups, 128 imgs) = 1024 blocks, 768 thr (12 waves), 3 planes/block.
__global__ __launch_bounds__(768, 2) void k_gw(
    const float* __restrict__ x, const h16* __restrict__ Kall, h16* __restrict__ P)
{
  __shared__ h16 As[96 * 200];
  const int half = blockIdx.x & 1, pg = blockIdx.x >> 1;
  const int img  = blockIdx.y;
  const int tid = threadIdx.x;
  const float* xi = x + (size_t)img * HW + (size_t)half * 96 * 192;
  for (int u = tid; u < 2304; u += 768) {        // u = r*24 + c8 : coalesced global reads
    int r = u / 24, c8 = u - r * 24;
    float4 v0 = *(const float4*)(xi + (size_t)r * 192 + c8 * 8);
    float4 v1 = *(const float4*)(xi + (size_t)r * 192 + c8 * 8 + 4);
    v8h h;
    h[0] = (h16)v0.x; h[1] = (h16)v0.y; h[2] = (h16)v0.z; h[3] = (h16)v0.w;
    h[4] = (h16)v1.x; h[5] = (h16)v1.y; h[6] = (h16)v1.z; h[7] = (h16)v1.w;
    *(v8h*)(As + (size_t)r * 200 + c8 * 8) = h;
  }
  __syncthreads();
  const int lane = tid & 63, wv = tid >> 6;      // 12 waves = (mt 0..5) x (nh 0..1)
  const int lm = lane & 15, quad = lane >> 4;
  const int mt = wv >> 1, nh = wv & 1;
  const int mrow = mt * 16;
  const int hg = half * 96 + mrow + quad * 4;
#pragma unroll
  for (int pl = 0; pl < 3; ++pl) {
    const int plane = pg * 3 + pl;
    const h16* KB = Kall + (size_t)plane * HW;
    h16* Pp = P + ((size_t)plane * IMGS + img) * HW;
#pragma unroll
    for (int t6 = 0; t6 < 6; ++t6) {
      const int n0 = (nh * 6 + t6) * 16;
      int kt0 = (n0 - 24) >> 5; kt0 = kt0 < 0 ? 0 : (kt0 > 3 ? 3 : kt0);
      v4f C = (v4f){0.f, 0.f, 0.f, 0.f};
#pragma unroll
      for (int kt = 0; kt < 3; ++kt) {
        const int k0 = (kt0 + kt) * 32 + quad * 8;
        v8h a = *(const v8h*)(As + (size_t)(mrow + lm) * 200 + k0);
        v8h b = *(const v8h*)(KB + (size_t)(n0 + lm) * 192 + k0);
        C = __builtin_amdgcn_mfma_f32_16x16x32_f16(a, b, C, 0, 0, 0);
      }
      const int q = n0 / 48;
      const int wq = n0 - q * 48 + lm;           // w' within quarter
      v4h o;
      o[0] = (h16)C[0]; o[1] = (h16)C[1]; o[2] = (h16)C[2]; o[3] = (h16)C[3];
      *(v4h*)(Pp + (size_t)q * 9216 + (size_t)wq * 192 + hg) = o;   // 4 consecutive h, 8B packed
    }
  }
}

// ---------------- pass H + gated combine: small independent barrier domains ----------------
// R8 lesson: no-LDS dies (compiler serializes loads; VGPR 52/76). R3's LDS version works but
// showed ~1.7 effective blocks/CU (21% occ) -> barrier lockstep exposes L2 latency. This
// round: split each block in half along m (mh) -> 2048 blocks x 256 thr (4 waves), SINGLE
// Bs buffer (19.2 KB), 2 barriers/cand. Register prefetch issued after barrier-1, consumed
// after barrier-2 (drain lands post-compute, R2/R3 overlap preserved). (256,4) -> 128-VGPR
// cap, ~110 used -> 4-5 independent blocks/CU.
__global__ __launch_bounds__(256, 4) void k_gh2(
    const h16* __restrict__ Kall, const h16* __restrict__ P, const h16* __restrict__ gate,
    const float* __restrict__ hfp, h16* __restrict__ sf)
{
  __shared__ h16 Bs[48 * 200];
  const int bx = blockIdx.x;
  const int sw = bx & 1, qt = (bx >> 1) & 3, mh = bx >> 3;   // mh 0..1: m-half
  const int img = blockIdx.y;
  const int bimg = img >> 5;
  const int tid = threadIdx.x;
  const int lane = tid & 63, wv = tid >> 6;
  const int lm = lane & 15, quad = lane >> 4;
  const int sh = wv & 1, w4h = wv >> 1;          // 4 waves: sh side x m-quarter-within-half
  const int w0q = qt * 48;
  const int mbase = mh * 96 + w4h * 48;          // this wave's 48-row m block

  // staging: 1152 v8h items over 256 threads (4.5/thread); item -> (wp 0..47, c8 0..23)
  const int wp0 = tid / 24,           c80 = tid - wp0 * 24;
  const int it1 = tid + 256;  const int wp1 = it1 / 24, c81 = it1 - wp1 * 24;
  const int it2 = tid + 512;  const int wp2 = it2 / 24, c82 = it2 - wp2 * 24;
  const int it3 = tid + 768;  const int wp3 = it3 / 24, c83 = it3 - wp3 * 24;
  const int it4 = tid + 1024; const int wp4 = it4 / 24, c84 = it4 - wp4 * 24;  // tid<128 only

  v4f acc[3][3];
#pragma unroll
  for (int mi = 0; mi < 3; ++mi)
#pragma unroll
    for (int nt = 0; nt < 3; ++nt) acc[mi][nt] = (v4f){0.f, 0.f, 0.f, 0.f};

  const h16* Ps = P + ((size_t)sw * IMGS + img) * HW + (size_t)qt * 9216;
  v8h p0 = *(const v8h*)(Ps + (size_t)wp0 * 192 + c80 * 8);
  v8h p1 = *(const v8h*)(Ps + (size_t)wp1 * 192 + c81 * 8);
  v8h p2 = *(const v8h*)(Ps + (size_t)wp2 * 192 + c82 * 8);
  v8h p3 = *(const v8h*)(Ps + (size_t)wp3 * 192 + c83 * 8);
  v8h p4;
  if (tid < 128) p4 = *(const v8h*)(Ps + (size_t)wp4 * 192 + c84 * 8);

  for (int cand = 0; cand < 6; ++cand) {
    *(v8h*)(Bs + (size_t)wp0 * 200 + c80 * 8) = p0;
    *(v8h*)(Bs + (size_t)wp1 * 200 + c81 * 8) = p1;
    *(v8h*)(Bs + (size_t)wp2 * 200 + c82 * 8) = p2;
    *(v8h*)(Bs + (size_t)wp3 * 200 + c83 * 8) = p3;
    if (tid < 128) *(v8h*)(Bs + (size_t)wp4 * 200 + c84 * 8) = p4;
    __syncthreads();   // Bs ready
    if (cand < 5) {    // issue next slice's loads now; HBM latency hides under compute below
      const h16* Pn = P + ((size_t)((cand + 1) * 2 + sw) * IMGS + img) * HW + (size_t)qt * 9216;
      p0 = *(const v8h*)(Pn + (size_t)wp0 * 192 + c80 * 8);
      p1 = *(const v8h*)(Pn + (size_t)wp1 * 192 + c81 * 8);
      p2 = *(const v8h*)(Pn + (size_t)wp2 * 192 + c82 * 8);
      p3 = *(const v8h*)(Pn + (size_t)wp3 * 192 + c83 * 8);
      if (tid < 128) p4 = *(const v8h*)(Pn + (size_t)wp4 * 192 + c84 * 8);
    }
    const h16* g16 = gate + (size_t)(bimg * 6 + cand) * HW;
    const h16* KB = Kall + (size_t)(cand * 2 + sh) * HW;
#pragma unroll
    for (int mi = 0; mi < 3; ++mi) {
      const int m0 = mbase + mi * 16;
      const int ktlo = imax(0, (m0 - 24) >> 5), kthi = imin(5, (m0 + 39) >> 5);
      const int hr0 = m0 + quad * 4;
      float g[3][4];
#pragma unroll
      for (int nt = 0; nt < 3; ++nt)
#pragma unroll
        for (int r = 0; r < 4; ++r)
          g[nt][r] = (float)g16[(size_t)(hr0 + r) * 192 + w0q + nt * 16 + lm];
      v4f C[3];
#pragma unroll
      for (int nt = 0; nt < 3; ++nt) C[nt] = (v4f){0.f, 0.f, 0.f, 0.f};
      for (int kt = ktlo; kt <= kthi; ++kt) {
        const int k0 = kt * 32 + quad * 8;
        v8h a = *(const v8h*)(KB + (size_t)(m0 + lm) * 192 + k0);
#pragma unroll
        for (int nt = 0; nt < 3; ++nt) {
          v8h b = *(const v8h*)(Bs + (size_t)(nt * 16 + lm) * 200 + k0);
          C[nt] = __builtin_amdgcn_mfma_f32_16x16x32_f16(a, b, C[nt], 0, 0, 0);
        }
      }
#pragma unroll
      for (int nt = 0; nt < 3; ++nt)
#pragma unroll
        for (int r = 0; r < 4; ++r)
          acc[mi][nt][r] += g[nt][r] * C[nt][r];
    }
    __syncthreads();   // compute done before next cand's ds_write (single buffer)
  }
  // epilogue: hf fold + fp16 store
  const float hfv = hfp[0];
  const int s = sw * 2 + sh;
  const float f = (s == 0) ? 1.f : hfv;
  h16* Op = sf + ((size_t)img * 4 + s) * HW;
#pragma unroll
  for (int mi = 0; mi < 3; ++mi) {
    const int hr0 = mbase + mi * 16 + quad * 4;
#pragma unroll
    for (int nt = 0; nt < 3; ++nt) {
      const int wc = w0q + nt * 16 + lm;
#pragma unroll
      for (int r = 0; r < 4; ++r)
        Op[(size_t)(hr0 + r) * 192 + wc] = (h16)(f * acc[mi][nt][r]);
    }
  }
}

// ---------------- final 1x1 projection 128 -> 32 (4 px/thread, v4h loads) ----------------
__global__ __launch_bounds__(256) void k_proj(
    const h16* __restrict__ sf, const float* __restrict__ pw,
    const float* __restrict__ pb, float* __restrict__ out)
{
  const int tid = threadIdx.x;
  const int lane = tid & 63;
  const int og = __builtin_amdgcn_readfirstlane(tid >> 6);   // 0..3, wave-uniform scalar
  const int b = blockIdx.x / 144;                             // 144 blocks per image (256 px each)
  const int p = (blockIdx.x - b * 144) * 256 + lane * 4;
  const h16* sfb = sf + (size_t)(b * 128) * HW + p;
  const float* pwb = pw + og * 8 * 128;                       // scalar base
  float acc[8][4];
#pragma unroll
  for (int oo = 0; oo < 8; ++oo)
#pragma unroll
    for (int j = 0; j < 4; ++j) acc[oo][j] = 0.f;
#pragma unroll 4
  for (int ch = 0; ch < 128; ++ch) {
    v4h hv = *(const v4h*)(sfb + (size_t)ch * HW);
    float v[4];
#pragma unroll
    for (int j = 0; j < 4; ++j) v[j] = (float)hv[j];
#pragma unroll
    for (int oo = 0; oo < 8; ++oo) {
      const float w = pwb[oo * 128 + ch];
#pragma unroll
      for (int j = 0; j < 4; ++j) acc[oo][j] = fmaf(w, v[j], acc[oo][j]);
    }
  }
#pragma unroll
  for (int oo = 0; oo < 8; ++oo) {
    const float bb = pb[og * 8 + oo];
    float4 o4;
    o4.x = acc[oo][0] + bb; o4.y = acc[oo][1] + bb;
    o4.z = acc[oo][2] + bb; o4.w = acc[oo][3] + bb;
    *(float4*)(out + (size_t)(b * 32 + og * 8 + oo) * HW + p) = o4;
  }
}

extern "C" void kernel_launch(void* const* d_in, const int* in_sizes, int n_in,
                              void* d_out, int out_size, void* d_ws, size_t ws_size,
                              hipStream_t stream) {
  (void)in_sizes; (void)n_in; (void)out_size; (void)ws_size;
  const float* x    = (const float*)d_in[0];
  const float* gw1  = (const float*)d_in[1];
  const float* gb1  = (const float*)d_in[2];
  const float* gw2  = (const float*)d_in[3];
  const float* gb2  = (const float*)d_in[4];
  const float* s53A = (const float*)d_in[5];
  const float* s53D = (const float*)d_in[6];
  const float* s97A = (const float*)d_in[7];
  const float* s97D = (const float*)d_in[8];
  const float* hfp  = (const float*)d_in[9];
  const float* pw   = (const float*)d_in[10];
  const float* pb   = (const float*)d_in[11];
  float* out = (float*)d_out;

  // workspace (bytes), total 153,649,152 (proven layout):
  //   gate fp16:          0 ..   1,769,472   (4 x 6 x HW)
  //   Kall fp16:  1,769,472 ..   2,654,208   (12 x 192 x 192)
  //   P    fp16:  2,654,208 .. 115,900,416   (12 x 128 x HW)  layout [plane][img][q4][w'48][h192]
  //   sf   fp16: 115,900,416 .. 153,649,152  (128 x 4 x HW)
  h16* gate = (h16*)d_ws;
  h16* Kall = (h16*)((char*)d_ws + 1769472);
  h16* P    = (h16*)((char*)d_ws + 2654208);
  h16* sf   = (h16*)((char*)d_ws + 115900416);

  hipLaunchKernelGGL(k_gate, dim3(576), dim3(256), 0, stream, x, gw1, gb1, gw2, gb2, gate);
  hipLaunchKernelGGL(k_build, dim3(192, 12), dim3(64), 0, stream, Kall, s53A, s53D, s97A, s97D);
  hipLaunchKernelGGL(k_gw, dim3(8, IMGS), dim3(768), 0, stream, x, Kall, P);
  hipLaunchKernelGGL(k_gh2, dim3(16, IMGS), dim3(256), 0, stream, Kall, P, gate, hfp, sf);
  hipLaunchKernelGGL(k_proj, dim3(576), dim3(256), 0, stream, sf, pw, pb, out);
}

// Round 10
// 313.396 us; speedup vs baseline: 1.5683x; 1.5683x over previous
//
#include <hip/hip_runtime.h>
#include <hip/hip_fp16.h>

#define HW 36864      // 192*192
#define IMGS 128      // B*C

typedef _Float16 h16;
typedef _Float16 v8h __attribute__((ext_vector_type(8)));
typedef _Float16 v4h __attribute__((ext_vector_type(4)));
typedef float v4f __attribute__((ext_vector_type(4)));

static __device__ __forceinline__ int imax(int a, int b) { return a > b ? a : b; }
static __device__ __forceinline__ int imin(int a, int b) { return a < b ? a : b; }

__device__ __constant__ float LIFT_C[6] = {
  -0.5f, 0.25f,                                            // bior53
  -1.586134342f, -0.05298011854f, 0.8829110762f, 0.4435068522f  // bior97
};
__device__ __constant__ int FIR_L[4]   = {8, 12, 12, 30};
__device__ __constant__ int FIR_PA[4]  = {2, 4, 4, 13};
__device__ __constant__ int FIR_OFF[4] = {0, 8, 20, 32};

// raw (unnormalized) FIR lowpass filters concatenated: db4(8) db6(12) sym6(12) coif5(30)
__device__ constexpr float FIRC[62] = {
  -0.0105974017850021f, 0.0328830116668852f, 0.0308413818355607f, -0.1870348117188811f,
  -0.0279837694169839f, 0.6308807679295904f, 0.7148465705529155f, 0.2303778133088964f,
  0.00107730108499558f, -0.00477725751101065f, -0.0005538422009938f, 0.03158203931748603f,
  0.02752286553030533f, -0.0975016055873225f, -0.12976686756709563f, 0.22626469396544f,
  0.3152503517092432f, -0.7511339080210959f, 0.4946238903984534f, 0.1115407433501095f,
  -0.007800708325034148f, 0.001767711864242804f, 0.04472490177066578f, -0.02106029251230056f,
  -0.0726375227866f, 0.3379294217282401f, 0.787641141030194f, 0.4910559419267466f,
  -0.048311742585632f, -0.1179901111484105f, 0.00349071208421747f, 0.01540410932702737f,
  -3.459977283621256e-05f, -7.098330313814114e-05f, 0.0004662169601128863f, 0.001117518770890601f,
  -0.002574517688750223f, -0.00900797613666158f, 0.015880544863615904f, 0.03455502757306163f,
  -0.08230192710688598f, -0.07179982161931202f, 0.42848347637761874f, 0.7937772226256206f,
  0.4051769024096169f, -0.06112339000267287f, -0.06577191128185562f, 0.023452696141836267f,
  0.007782596427325418f, -0.003793512864491014f, -0.0002606761356811993f, 0.000107502882505652f,
  1.10319778524429e-05f, -5.520763127949e-06f, -1.0682196848076e-06f, 5.236425333584e-07f,
  1.125098976034e-07f, -5.417490769329e-08f, -8.8631e-09f, 4.2921e-09f, 6.7e-10f, -3.2e-10f,
};

// ---------------- gate: 1x1 conv -> relu -> 1x1 conv -> softmax -> renorm (fp16 out) ----------------
__global__ __launch_bounds__(256) void k_gate(
    const float* __restrict__ x, const float* __restrict__ w1, const float* __restrict__ b1,
    const float* __restrict__ w2, const float* __restrict__ b2, h16* __restrict__ gate)
{
  __shared__ float w1s[256], b1s[8], w2s[48], b2s[6];
  int tid = threadIdx.x;
  w1s[tid] = w1[tid];
  if (tid < 8)  b1s[tid] = b1[tid];
  if (tid < 48) w2s[tid] = w2[tid];
  if (tid < 6)  b2s[tid] = b2[tid];
  __syncthreads();
  int px = blockIdx.x * 256 + tid;        // exactly 4*HW threads
  int b = px / HW, p = px - b * HW;
  const float* xb = x + (size_t)b * 32 * HW + p;
  float xv[32];
#pragma unroll
  for (int c = 0; c < 32; ++c) xv[c] = xb[(size_t)c * HW];
  float hb[8];
#pragma unroll
  for (int j = 0; j < 8; ++j) {
    float s = b1s[j];
#pragma unroll
    for (int c = 0; c < 32; ++c) s += w1s[j * 32 + c] * xv[c];
    hb[j] = fmaxf(s, 0.f);
  }
  float e[6], mx = -1e30f;
#pragma unroll
  for (int k = 0; k < 6; ++k) {
    float s = b2s[k];
#pragma unroll
    for (int j = 0; j < 8; ++j) s += w2s[k * 8 + j] * hb[j];
    e[k] = s; mx = fmaxf(mx, s);
  }
  float se = 0.f;
#pragma unroll
  for (int k = 0; k < 6; ++k) { e[k] = expf(e[k] - mx); se += e[k]; }
  float inv = 1.f / se, s2 = 0.f;
#pragma unroll
  for (int k = 0; k < 6; ++k) { e[k] *= inv; s2 += e[k]; }
  float inv2 = 1.f / (s2 + 1e-12f);
  h16* gp = gate + (size_t)b * 6 * HW + p;
#pragma unroll
  for (int k = 0; k < 6; ++k) gp[(size_t)k * HW] = (h16)(e[k] * inv2);
}

// ---------------- build the 12 operator matrices (fp16, 192x192 row-major [out][in]) ----------------
__global__ __launch_bounds__(64) void k_build(
    h16* __restrict__ Kall, const float* __restrict__ s53A, const float* __restrict__ s53D,
    const float* __restrict__ s97A, const float* __restrict__ s97D)
{
  const int col = blockIdx.x;      // 0..191 (input index)
  const int mat = blockIdx.y;      // 0..11
  const int cand = mat >> 1, side = mat & 1;
  const int tid = threadIdx.x;
  h16* out = Kall + (size_t)mat * HW;
  if (cand < 4) {
    const int Lf = FIR_L[cand], PA = FIR_PA[cand], OFF = FIR_OFF[cand];
    float ss = 0.f;
    for (int j = 0; j < Lf; ++j) ss += FIRC[OFF + j] * FIRC[OFF + j];
    const float invn = 1.f / (sqrtf(ss) + 1e-12f);
    for (int i = tid; i < 192; i += 64) {
      const int d = (i < 96) ? 1 : 2;
      const int q0 = i - d;
      const int i0 = imax(q0, 0), i1 = imin(q0 + 1, 189);
      const float tt = (float)d - (float)(2 * i + 1) * (1.f / 192.f);
      float c0 = 0.f, c1 = 0.f;
      for (int j = 0; j < Lf; ++j) {
        float fj = side ? (((j & 1) ? -1.f : 1.f) * FIRC[OFF + Lf - 1 - j]) : FIRC[OFF + j];
        fj *= invn;
        int r0 = i0 + j - PA; r0 = r0 < 0 ? -r0 : (r0 > 191 ? 382 - r0 : r0);
        int r1 = i1 + j - PA; r1 = r1 < 0 ? -r1 : (r1 > 191 ? 382 - r1 : r1);
        if (r0 == col) c0 += fj;
        if (r1 == col) c1 += fj;
      }
      out[(size_t)i * 192 + col] = (h16)((1.f - tt) * c0 + tt * c1);
    }
  } else {
    __shared__ float yb[192];
    __shared__ float sb[96];
    yb[tid] = 0.f; yb[tid + 64] = 0.f; yb[tid + 128] = 0.f;
    __syncthreads();
    if (tid == 0) yb[col] = 1.f;
    __syncthreads();
    const int c97 = (cand == 5);
    const int base = c97 ? 2 : 0, ns = c97 ? 4 : 2;
    for (int s = 0; s < ns; ++s) {
      const float cf = LIFT_C[base + s] * 0.5f;
      for (int j = tid; j < 96; j += 64) {
        int jm = (j == 0) ? 1 : j - 1, jp = (j == 95) ? 94 : j + 1;
        if ((s & 1) == 0) yb[2 * j + 1] += cf * (yb[2 * jm] + yb[2 * jp]);
        else              yb[2 * j]     += cf * (yb[2 * jm + 1] + yb[2 * jp + 1]);
      }
      __syncthreads();
    }
    const float sA = c97 ? s97A[0] : s53A[0];
    const float sD = c97 ? s97D[0] : s53D[0];
    for (int u = tid; u < 96; u += 64)
      sb[u] = side ? sD * yb[2 * u + 1] : sA * yb[2 * u];
    __syncthreads();
    for (int i = tid; i < 192; i += 64) {
      const int u0 = (i >> 1) + (i & 1) - 1;
      const float tt = (i & 1) ? 0.25f : 0.75f;
      const int a0 = imax(u0, 0), a1 = imin(u0 + 1, 95);
      out[(size_t)i * 192 + col] = (h16)((1.f - tt) * sb[a0] + tt * sb[a1]);
    }
  }
}

// ---------------- pass W (R3-proven, byte-identical to the 305.8us run) ----------------
// grid (2 half x 4 plane-groups, 128 imgs) = 1024 blocks, 768 thr (12 waves), 3 planes/block.
__global__ __launch_bounds__(768, 2) void k_gw(
    const float* __restrict__ x, const h16* __restrict__ Kall, h16* __restrict__ P)
{
  __shared__ h16 As[96 * 200];
  const int half = blockIdx.x & 1, pg = blockIdx.x >> 1;
  const int img  = blockIdx.y;
  const int tid = threadIdx.x;
  const float* xi = x + (size_t)img * HW + (size_t)half * 96 * 192;
  for (int u = tid; u < 2304; u += 768) {        // u = r*24 + c8 : coalesced global reads
    int r = u / 24, c8 = u - r * 24;
    float4 v0 = *(const float4*)(xi + (size_t)r * 192 + c8 * 8);
    float4 v1 = *(const float4*)(xi + (size_t)r * 192 + c8 * 8 + 4);
    v8h h;
    h[0] = (h16)v0.x; h[1] = (h16)v0.y; h[2] = (h16)v0.z; h[3] = (h16)v0.w;
    h[4] = (h16)v1.x; h[5] = (h16)v1.y; h[6] = (h16)v1.z; h[7] = (h16)v1.w;
    *(v8h*)(As + (size_t)r * 200 + c8 * 8) = h;
  }
  __syncthreads();
  const int lane = tid & 63, wv = tid >> 6;      // 12 waves = (mt 0..5) x (nh 0..1)
  const int lm = lane & 15, quad = lane >> 4;
  const int mt = wv >> 1, nh = wv & 1;
  const int mrow = mt * 16;
  const int hg = half * 96 + mrow + quad * 4;
#pragma unroll
  for (int pl = 0; pl < 3; ++pl) {
    const int plane = pg * 3 + pl;
    const h16* KB = Kall + (size_t)plane * HW;
    h16* Pp = P + ((size_t)plane * IMGS + img) * HW;
#pragma unroll
    for (int t6 = 0; t6 < 6; ++t6) {
      const int n0 = (nh * 6 + t6) * 16;
      int kt0 = (n0 - 24) >> 5; kt0 = kt0 < 0 ? 0 : (kt0 > 3 ? 3 : kt0);
      v4f C = (v4f){0.f, 0.f, 0.f, 0.f};
#pragma unroll
      for (int kt = 0; kt < 3; ++kt) {
        const int k0 = (kt0 + kt) * 32 + quad * 8;
        v8h a = *(const v8h*)(As + (size_t)(mrow + lm) * 200 + k0);
        v8h b = *(const v8h*)(KB + (size_t)(n0 + lm) * 192 + k0);
        C = __builtin_amdgcn_mfma_f32_16x16x32_f16(a, b, C, 0, 0, 0);
      }
      const int q = n0 / 48;
      const int wq = n0 - q * 48 + lm;           // w' within quarter
      v4h o;
      o[0] = (h16)C[0]; o[1] = (h16)C[1]; o[2] = (h16)C[2]; o[3] = (h16)C[3];
      *(v4h*)(Pp + (size_t)q * 9216 + (size_t)wq * 192 + hg) = o;   // 4 consecutive h, 8B packed
    }
  }
}

// ---------------- pass H + gated combine: small independent barrier domains ----------------
// R9 structure, ONE token changed: __launch_bounds__(256, 2). R9's (256,4) imposed a 64-VGPR
// cap (calibration: 2nd-arg 4 -> 64 cap; 2nd-arg 2 -> 128+ cap) -> ~1 GB scratch spill.
// With cap 256: ~110 live VGPRs fit, LDS 19.5 KB -> 4 blocks/CU = 16 waves in 4 independent
// barrier domains (vs R3's 1.7). 2048 blocks x 256 thr (4 waves), single Bs, 2 barriers/cand;
// prefetch issued after barrier-1, consumed next iter (R2/R3-proven overlap).
__global__ __launch_bounds__(256, 2) void k_gh2(
    const h16* __restrict__ Kall, const h16* __restrict__ P, const h16* __restrict__ gate,
    const float* __restrict__ hfp, h16* __restrict__ sf)
{
  __shared__ h16 Bs[48 * 200];
  const int bx = blockIdx.x;
  const int sw = bx & 1, qt = (bx >> 1) & 3, mh = bx >> 3;   // mh 0..1: m-half
  const int img = blockIdx.y;
  const int bimg = img >> 5;
  const int tid = threadIdx.x;
  const int lane = tid & 63, wv = tid >> 6;
  const int lm = lane & 15, quad = lane >> 4;
  const int sh = wv & 1, w4h = wv >> 1;          // 4 waves: sh side x m-quarter-within-half
  const int w0q = qt * 48;
  const int mbase = mh * 96 + w4h * 48;          // this wave's 48-row m block

  // staging: 1152 v8h items over 256 threads (4.5/thread); item -> (wp 0..47, c8 0..23)
  const int wp0 = tid / 24,           c80 = tid - wp0 * 24;
  const int it1 = tid + 256;  const int wp1 = it1 / 24, c81 = it1 - wp1 * 24;
  const int it2 = tid + 512;  const int wp2 = it2 / 24, c82 = it2 - wp2 * 24;
  const int it3 = tid + 768;  const int wp3 = it3 / 24, c83 = it3 - wp3 * 24;
  const int it4 = tid + 1024; const int wp4 = it4 / 24, c84 = it4 - wp4 * 24;  // tid<128 only

  v4f acc[3][3];
#pragma unroll
  for (int mi = 0; mi < 3; ++mi)
#pragma unroll
    for (int nt = 0; nt < 3; ++nt) acc[mi][nt] = (v4f){0.f, 0.f, 0.f, 0.f};

  const h16* Ps = P + ((size_t)sw * IMGS + img) * HW + (size_t)qt * 9216;
  v8h p0 = *(const v8h*)(Ps + (size_t)wp0 * 192 + c80 * 8);
  v8h p1 = *(const v8h*)(Ps + (size_t)wp1 * 192 + c81 * 8);
  v8h p2 = *(const v8h*)(Ps + (size_t)wp2 * 192 + c82 * 8);
  v8h p3 = *(const v8h*)(Ps + (size_t)wp3 * 192 + c83 * 8);
  v8h p4;
  if (tid < 128) p4 = *(const v8h*)(Ps + (size_t)wp4 * 192 + c84 * 8);

  for (int cand = 0; cand < 6; ++cand) {
    *(v8h*)(Bs + (size_t)wp0 * 200 + c80 * 8) = p0;
    *(v8h*)(Bs + (size_t)wp1 * 200 + c81 * 8) = p1;
    *(v8h*)(Bs + (size_t)wp2 * 200 + c82 * 8) = p2;
    *(v8h*)(Bs + (size_t)wp3 * 200 + c83 * 8) = p3;
    if (tid < 128) *(v8h*)(Bs + (size_t)wp4 * 200 + c84 * 8) = p4;
    __syncthreads();   // Bs ready
    if (cand < 5) {    // issue next slice's loads now; HBM latency hides under compute below
      const h16* Pn = P + ((size_t)((cand + 1) * 2 + sw) * IMGS + img) * HW + (size_t)qt * 9216;
      p0 = *(const v8h*)(Pn + (size_t)wp0 * 192 + c80 * 8);
      p1 = *(const v8h*)(Pn + (size_t)wp1 * 192 + c81 * 8);
      p2 = *(const v8h*)(Pn + (size_t)wp2 * 192 + c82 * 8);
      p3 = *(const v8h*)(Pn + (size_t)wp3 * 192 + c83 * 8);
      if (tid < 128) p4 = *(const v8h*)(Pn + (size_t)wp4 * 192 + c84 * 8);
    }
    const h16* g16 = gate + (size_t)(bimg * 6 + cand) * HW;
    const h16* KB = Kall + (size_t)(cand * 2 + sh) * HW;
#pragma unroll
    for (int mi = 0; mi < 3; ++mi) {
      const int m0 = mbase + mi * 16;
      const int ktlo = imax(0, (m0 - 24) >> 5), kthi = imin(5, (m0 + 39) >> 5);
      const int hr0 = m0 + quad * 4;
      float g[3][4];
#pragma unroll
      for (int nt = 0; nt < 3; ++nt)
#pragma unroll
        for (int r = 0; r < 4; ++r)
          g[nt][r] = (float)g16[(size_t)(hr0 + r) * 192 + w0q + nt * 16 + lm];
      v4f C[3];
#pragma unroll
      for (int nt = 0; nt < 3; ++nt) C[nt] = (v4f){0.f, 0.f, 0.f, 0.f};
      for (int kt = ktlo; kt <= kthi; ++kt) {
        const int k0 = kt * 32 + quad * 8;
        v8h a = *(const v8h*)(KB + (size_t)(m0 + lm) * 192 + k0);
#pragma unroll
        for (int nt = 0; nt < 3; ++nt) {
          v8h b = *(const v8h*)(Bs + (size_t)(nt * 16 + lm) * 200 + k0);
          C[nt] = __builtin_amdgcn_mfma_f32_16x16x32_f16(a, b, C[nt], 0, 0, 0);
        }
      }
#pragma unroll
      for (int nt = 0; nt < 3; ++nt)
#pragma unroll
        for (int r = 0; r < 4; ++r)
          acc[mi][nt][r] += g[nt][r] * C[nt][r];
    }
    __syncthreads();   // compute done before next cand's ds_write (single buffer)
  }
  // epilogue: hf fold + fp16 store
  const float hfv = hfp[0];
  const int s = sw * 2 + sh;
  const float f = (s == 0) ? 1.f : hfv;
  h16* Op = sf + ((size_t)img * 4 + s) * HW;
#pragma unroll
  for (int mi = 0; mi < 3; ++mi) {
    const int hr0 = mbase + mi * 16 + quad * 4;
#pragma unroll
    for (int nt = 0; nt < 3; ++nt) {
      const int wc = w0q + nt * 16 + lm;
#pragma unroll
      for (int r = 0; r < 4; ++r)
        Op[(size_t)(hr0 + r) * 192 + wc] = (h16)(f * acc[mi][nt][r]);
    }
  }
}

// ---------------- final 1x1 projection 128 -> 32 (4 px/thread, v4h loads) ----------------
__global__ __launch_bounds__(256) void k_proj(
    const h16* __restrict__ sf, const float* __restrict__ pw,
    const float* __restrict__ pb, float* __restrict__ out)
{
  const int tid = threadIdx.x;
  const int lane = tid & 63;
  const int og = __builtin_amdgcn_readfirstlane(tid >> 6);   // 0..3, wave-uniform scalar
  const int b = blockIdx.x / 144;                             // 144 blocks per image (256 px each)
  const int p = (blockIdx.x - b * 144) * 256 + lane * 4;
  const h16* sfb = sf + (size_t)(b * 128) * HW + p;
  const float* pwb = pw + og * 8 * 128;                       // scalar base
  float acc[8][4];
#pragma unroll
  for (int oo = 0; oo < 8; ++oo)
#pragma unroll
    for (int j = 0; j < 4; ++j) acc[oo][j] = 0.f;
#pragma unroll 4
  for (int ch = 0; ch < 128; ++ch) {
    v4h hv = *(const v4h*)(sfb + (size_t)ch * HW);
    float v[4];
#pragma unroll
    for (int j = 0; j < 4; ++j) v[j] = (float)hv[j];
#pragma unroll
    for (int oo = 0; oo < 8; ++oo) {
      const float w = pwb[oo * 128 + ch];
#pragma unroll
      for (int j = 0; j < 4; ++j) acc[oo][j] = fmaf(w, v[j], acc[oo][j]);
    }
  }
#pragma unroll
  for (int oo = 0; oo < 8; ++oo) {
    const float bb = pb[og * 8 + oo];
    float4 o4;
    o4.x = acc[oo][0] + bb; o4.y = acc[oo][1] + bb;
    o4.z = acc[oo][2] + bb; o4.w = acc[oo][3] + bb;
    *(float4*)(out + (size_t)(b * 32 + og * 8 + oo) * HW + p) = o4;
  }
}

extern "C" void kernel_launch(void* const* d_in, const int* in_sizes, int n_in,
                              void* d_out, int out_size, void* d_ws, size_t ws_size,
                              hipStream_t stream) {
  (void)in_sizes; (void)n_in; (void)out_size; (void)ws_size;
  const float* x    = (const float*)d_in[0];
  const float* gw1  = (const float*)d_in[1];
  const float* gb1  = (const float*)d_in[2];
  const float* gw2  = (const float*)d_in[3];
  const float* gb2  = (const float*)d_in[4];
  const float* s53A = (const float*)d_in[5];
  const float* s53D = (const float*)d_in[6];
  const float* s97A = (const float*)d_in[7];
  const float* s97D = (const float*)d_in[8];
  const float* hfp  = (const float*)d_in[9];
  const float* pw   = (const float*)d_in[10];
  const float* pb   = (const float*)d_in[11];
  float* out = (float*)d_out;

  // workspace (bytes), total 153,649,152 (proven layout):
  //   gate fp16:          0 ..   1,769,472   (4 x 6 x HW)
  //   Kall fp16:  1,769,472 ..   2,654,208   (12 x 192 x 192)
  //   P    fp16:  2,654,208 .. 115,900,416   (12 x 128 x HW)  layout [plane][img][q4][w'48][h192]
  //   sf   fp16: 115,900,416 .. 153,649,152  (128 x 4 x HW)
  h16* gate = (h16*)d_ws;
  h16* Kall = (h16*)((char*)d_ws + 1769472);
  h16* P    = (h16*)((char*)d_ws + 2654208);
  h16* sf   = (h16*)((char*)d_ws + 115900416);

  hipLaunchKernelGGL(k_gate, dim3(576), dim3(256), 0, stream, x, gw1, gb1, gw2, gb2, gate);
  hipLaunchKernelGGL(k_build, dim3(192, 12), dim3(64), 0, stream, Kall, s53A, s53D, s97A, s97D);
  hipLaunchKernelGGL(k_gw, dim3(8, IMGS), dim3(768), 0, stream, x, Kall, P);
  hipLaunchKernelGGL(k_gh2, dim3(16, IMGS), dim3(256), 0, stream, Kall, P, gate, hfp, sf);
  hipLaunchKernelGGL(k_proj, dim3(576), dim3(256), 0, stream, sf, pw, pb, out);
}

// Round 11
// 277.138 us; speedup vs baseline: 1.7735x; 1.1308x over previous
//
#include <hip/hip_runtime.h>
#include <hip/hip_fp16.h>

#define HW 36864      // 192*192
#define IMGS 128      // B*C

typedef _Float16 h16;
typedef _Float16 v8h __attribute__((ext_vector_type(8)));
typedef _Float16 v4h __attribute__((ext_vector_type(4)));
typedef float v4f __attribute__((ext_vector_type(4)));

static __device__ __forceinline__ int imax(int a, int b) { return a > b ? a : b; }
static __device__ __forceinline__ int imin(int a, int b) { return a < b ? a : b; }

__device__ __constant__ float LIFT_C[6] = {
  -0.5f, 0.25f,                                            // bior53
  -1.586134342f, -0.05298011854f, 0.8829110762f, 0.4435068522f  // bior97
};
__device__ __constant__ int FIR_L[4]   = {8, 12, 12, 30};
__device__ __constant__ int FIR_PA[4]  = {2, 4, 4, 13};
__device__ __constant__ int FIR_OFF[4] = {0, 8, 20, 32};

// raw (unnormalized) FIR lowpass filters concatenated: db4(8) db6(12) sym6(12) coif5(30)
__device__ constexpr float FIRC[62] = {
  -0.0105974017850021f, 0.0328830116668852f, 0.0308413818355607f, -0.1870348117188811f,
  -0.0279837694169839f, 0.6308807679295904f, 0.7148465705529155f, 0.2303778133088964f,
  0.00107730108499558f, -0.00477725751101065f, -0.0005538422009938f, 0.03158203931748603f,
  0.02752286553030533f, -0.0975016055873225f, -0.12976686756709563f, 0.22626469396544f,
  0.3152503517092432f, -0.7511339080210959f, 0.4946238903984534f, 0.1115407433501095f,
  -0.007800708325034148f, 0.001767711864242804f, 0.04472490177066578f, -0.02106029251230056f,
  -0.0726375227866f, 0.3379294217282401f, 0.787641141030194f, 0.4910559419267466f,
  -0.048311742585632f, -0.1179901111484105f, 0.00349071208421747f, 0.01540410932702737f,
  -3.459977283621256e-05f, -7.098330313814114e-05f, 0.0004662169601128863f, 0.001117518770890601f,
  -0.002574517688750223f, -0.00900797613666158f, 0.015880544863615904f, 0.03455502757306163f,
  -0.08230192710688598f, -0.07179982161931202f, 0.42848347637761874f, 0.7937772226256206f,
  0.4051769024096169f, -0.06112339000267287f, -0.06577191128185562f, 0.023452696141836267f,
  0.007782596427325418f, -0.003793512864491014f, -0.0002606761356811993f, 0.000107502882505652f,
  1.10319778524429e-05f, -5.520763127949e-06f, -1.0682196848076e-06f, 5.236425333584e-07f,
  1.125098976034e-07f, -5.417490769329e-08f, -8.8631e-09f, 4.2921e-09f, 6.7e-10f, -3.2e-10f,
};

// ---------------- gate: 1x1 conv -> relu -> 1x1 conv -> softmax -> renorm (fp16 out) ----------------
__global__ __launch_bounds__(256) void k_gate(
    const float* __restrict__ x, const float* __restrict__ w1, const float* __restrict__ b1,
    const float* __restrict__ w2, const float* __restrict__ b2, h16* __restrict__ gate)
{
  __shared__ float w1s[256], b1s[8], w2s[48], b2s[6];
  int tid = threadIdx.x;
  w1s[tid] = w1[tid];
  if (tid < 8)  b1s[tid] = b1[tid];
  if (tid < 48) w2s[tid] = w2[tid];
  if (tid < 6)  b2s[tid] = b2[tid];
  __syncthreads();
  int px = blockIdx.x * 256 + tid;        // exactly 4*HW threads
  int b = px / HW, p = px - b * HW;
  const float* xb = x + (size_t)b * 32 * HW + p;
  float xv[32];
#pragma unroll
  for (int c = 0; c < 32; ++c) xv[c] = xb[(size_t)c * HW];
  float hb[8];
#pragma unroll
  for (int j = 0; j < 8; ++j) {
    float s = b1s[j];
#pragma unroll
    for (int c = 0; c < 32; ++c) s += w1s[j * 32 + c] * xv[c];
    hb[j] = fmaxf(s, 0.f);
  }
  float e[6], mx = -1e30f;
#pragma unroll
  for (int k = 0; k < 6; ++k) {
    float s = b2s[k];
#pragma unroll
    for (int j = 0; j < 8; ++j) s += w2s[k * 8 + j] * hb[j];
    e[k] = s; mx = fmaxf(mx, s);
  }
  float se = 0.f;
#pragma unroll
  for (int k = 0; k < 6; ++k) { e[k] = expf(e[k] - mx); se += e[k]; }
  float inv = 1.f / se, s2 = 0.f;
#pragma unroll
  for (int k = 0; k < 6; ++k) { e[k] *= inv; s2 += e[k]; }
  float inv2 = 1.f / (s2 + 1e-12f);
  h16* gp = gate + (size_t)b * 6 * HW + p;
#pragma unroll
  for (int k = 0; k < 6; ++k) gp[(size_t)k * HW] = (h16)(e[k] * inv2);
}

// ---------------- build the 12 operator matrices (fp16, 192x192 row-major [out][in]) ----------------
__global__ __launch_bounds__(64) void k_build(
    h16* __restrict__ Kall, const float* __restrict__ s53A, const float* __restrict__ s53D,
    const float* __restrict__ s97A, const float* __restrict__ s97D)
{
  const int col = blockIdx.x;      // 0..191 (input index)
  const int mat = blockIdx.y;      // 0..11
  const int cand = mat >> 1, side = mat & 1;
  const int tid = threadIdx.x;
  h16* out = Kall + (size_t)mat * HW;
  if (cand < 4) {
    const int Lf = FIR_L[cand], PA = FIR_PA[cand], OFF = FIR_OFF[cand];
    float ss = 0.f;
    for (int j = 0; j < Lf; ++j) ss += FIRC[OFF + j] * FIRC[OFF + j];
    const float invn = 1.f / (sqrtf(ss) + 1e-12f);
    for (int i = tid; i < 192; i += 64) {
      const int d = (i < 96) ? 1 : 2;
      const int q0 = i - d;
      const int i0 = imax(q0, 0), i1 = imin(q0 + 1, 189);
      const float tt = (float)d - (float)(2 * i + 1) * (1.f / 192.f);
      float c0 = 0.f, c1 = 0.f;
      for (int j = 0; j < Lf; ++j) {
        float fj = side ? (((j & 1) ? -1.f : 1.f) * FIRC[OFF + Lf - 1 - j]) : FIRC[OFF + j];
        fj *= invn;
        int r0 = i0 + j - PA; r0 = r0 < 0 ? -r0 : (r0 > 191 ? 382 - r0 : r0);
        int r1 = i1 + j - PA; r1 = r1 < 0 ? -r1 : (r1 > 191 ? 382 - r1 : r1);
        if (r0 == col) c0 += fj;
        if (r1 == col) c1 += fj;
      }
      out[(size_t)i * 192 + col] = (h16)((1.f - tt) * c0 + tt * c1);
    }
  } else {
    __shared__ float yb[192];
    __shared__ float sb[96];
    yb[tid] = 0.f; yb[tid + 64] = 0.f; yb[tid + 128] = 0.f;
    __syncthreads();
    if (tid == 0) yb[col] = 1.f;
    __syncthreads();
    const int c97 = (cand == 5);
    const int base = c97 ? 2 : 0, ns = c97 ? 4 : 2;
    for (int s = 0; s < ns; ++s) {
      const float cf = LIFT_C[base + s] * 0.5f;
      for (int j = tid; j < 96; j += 64) {
        int jm = (j == 0) ? 1 : j - 1, jp = (j == 95) ? 94 : j + 1;
        if ((s & 1) == 0) yb[2 * j + 1] += cf * (yb[2 * jm] + yb[2 * jp]);
        else              yb[2 * j]     += cf * (yb[2 * jm + 1] + yb[2 * jp + 1]);
      }
      __syncthreads();
    }
    const float sA = c97 ? s97A[0] : s53A[0];
    const float sD = c97 ? s97D[0] : s53D[0];
    for (int u = tid; u < 96; u += 64)
      sb[u] = side ? sD * yb[2 * u + 1] : sA * yb[2 * u];
    __syncthreads();
    for (int i = tid; i < 192; i += 64) {
      const int u0 = (i >> 1) + (i & 1) - 1;
      const float tt = (i & 1) ? 0.25f : 0.75f;
      const int a0 = imax(u0, 0), a1 = imin(u0 + 1, 95);
      out[(size_t)i * 192 + col] = (h16)((1.f - tt) * sb[a0] + tt * sb[a1]);
    }
  }
}

// ---------------- pass W: P[plane][img][q][w'][h] = sum_w K[plane][w'][w] * x[img][h][w] ----------
// R8's single-wave register-batched version (R8-validated; its "rest" was 38us faster than
// the LDS gw), with (a) the hc loop lifted into the grid -- no reuse across hc, so this
// triples wave parallelism for free: (12 mt x 3 hc, 128 img) = 4608 blocks, 18 waves/CU --
// and (b) stores re-indexed to the q-blocked P layout consumed by k_gh2.
// Per block: batch-load b[4][3] (12 distinct v8h regs, in flight together -- R4/R8 lesson:
// named-register batches pipeline, per-use loads serialize), loop 12 planes reusing b.
// mfma(a=K-frag, b=x-frag): out row = w' (quad*4+r), col = h (lm)  [R5-proven rule].
__global__ __launch_bounds__(64) void k_gw(
    const float* __restrict__ x, const h16* __restrict__ Kall, h16* __restrict__ P)
{
  const int bx = blockIdx.x;
  const int mt = bx % 12, hc = bx / 12;          // w'-tile, h-chunk
  const int img = blockIdx.y;
  const int lane = threadIdx.x;
  const int lm = lane & 15, quad = lane >> 4;
  const int m0 = mt * 16;                        // w' tile base
  int ktr = (m0 - 24) >> 5; ktr = ktr < 0 ? 0 : (ktr > 3 ? 3 : ktr);   // 3-slot band window
  const int q = mt / 3;                          // output quarter (m0 = 16*mt stays within q)
  const int wqb = m0 - q * 48;                   // w' base within quarter
  const float* xi = x + (size_t)img * HW;

  v8h b[4][3];
#pragma unroll
  for (int j = 0; j < 4; ++j)
#pragma unroll
    for (int kt = 0; kt < 3; ++kt) {
      const float* xr = xi + (size_t)(hc * 64 + j * 16 + lm) * 192 + (ktr + kt) * 32 + quad * 8;
      float4 u0 = *(const float4*)xr;
      float4 u1 = *(const float4*)(xr + 4);
      v8h t;
      t[0] = (h16)u0.x; t[1] = (h16)u0.y; t[2] = (h16)u0.z; t[3] = (h16)u0.w;
      t[4] = (h16)u1.x; t[5] = (h16)u1.y; t[6] = (h16)u1.z; t[7] = (h16)u1.w;
      b[j][kt] = t;
    }
#pragma unroll 2
  for (int plane = 0; plane < 12; ++plane) {
    const h16* KW = Kall + (size_t)plane * HW + (size_t)(m0 + lm) * 192 + ktr * 32 + quad * 8;
    v8h a0 = *(const v8h*)(KW);
    v8h a1 = *(const v8h*)(KW + 32);
    v8h a2 = *(const v8h*)(KW + 64);
    v4f C[4];
#pragma unroll
    for (int j = 0; j < 4; ++j) C[j] = (v4f){0.f, 0.f, 0.f, 0.f};
#pragma unroll
    for (int j = 0; j < 4; ++j) {
      C[j] = __builtin_amdgcn_mfma_f32_16x16x32_f16(a0, b[j][0], C[j], 0, 0, 0);
      C[j] = __builtin_amdgcn_mfma_f32_16x16x32_f16(a1, b[j][1], C[j], 0, 0, 0);
      C[j] = __builtin_amdgcn_mfma_f32_16x16x32_f16(a2, b[j][2], C[j], 0, 0, 0);
    }
    h16* Pp = P + ((size_t)plane * IMGS + img) * HW + (size_t)q * 9216;
#pragma unroll
    for (int j = 0; j < 4; ++j)
#pragma unroll
      for (int r = 0; r < 4; ++r)
        Pp[(size_t)(wqb + quad * 4 + r) * 192 + hc * 64 + j * 16 + lm] = (h16)C[j][r];
  }
}

// ---------------- pass H + gated combine (R10-proven, byte-identical: 100.5us) ----------------
// 2048 blocks x 256 thr (4 waves), single Bs, 2 barriers/cand; prefetch issued after
// barrier-1, consumed next iter. __launch_bounds__(256,2): 2nd-arg calibration -- 4 -> 64-VGPR
// cap (spills, R1/R9); 2 -> 128+ cap (VGPR 112, no spill, R10).
__global__ __launch_bounds__(256, 2) void k_gh2(
    const h16* __restrict__ Kall, const h16* __restrict__ P, const h16* __restrict__ gate,
    const float* __restrict__ hfp, h16* __restrict__ sf)
{
  __shared__ h16 Bs[48 * 200];
  const int bx = blockIdx.x;
  const int sw = bx & 1, qt = (bx >> 1) & 3, mh = bx >> 3;   // mh 0..1: m-half
  const int img = blockIdx.y;
  const int bimg = img >> 5;
  const int tid = threadIdx.x;
  const int lane = tid & 63, wv = tid >> 6;
  const int lm = lane & 15, quad = lane >> 4;
  const int sh = wv & 1, w4h = wv >> 1;          // 4 waves: sh side x m-quarter-within-half
  const int w0q = qt * 48;
  const int mbase = mh * 96 + w4h * 48;          // this wave's 48-row m block

  // staging: 1152 v8h items over 256 threads (4.5/thread); item -> (wp 0..47, c8 0..23)
  const int wp0 = tid / 24,           c80 = tid - wp0 * 24;
  const int it1 = tid + 256;  const int wp1 = it1 / 24, c81 = it1 - wp1 * 24;
  const int it2 = tid + 512;  const int wp2 = it2 / 24, c82 = it2 - wp2 * 24;
  const int it3 = tid + 768;  const int wp3 = it3 / 24, c83 = it3 - wp3 * 24;
  const int it4 = tid + 1024; const int wp4 = it4 / 24, c84 = it4 - wp4 * 24;  // tid<128 only

  v4f acc[3][3];
#pragma unroll
  for (int mi = 0; mi < 3; ++mi)
#pragma unroll
    for (int nt = 0; nt < 3; ++nt) acc[mi][nt] = (v4f){0.f, 0.f, 0.f, 0.f};

  const h16* Ps = P + ((size_t)sw * IMGS + img) * HW + (size_t)qt * 9216;
  v8h p0 = *(const v8h*)(Ps + (size_t)wp0 * 192 + c80 * 8);
  v8h p1 = *(const v8h*)(Ps + (size_t)wp1 * 192 + c81 * 8);
  v8h p2 = *(const v8h*)(Ps + (size_t)wp2 * 192 + c82 * 8);
  v8h p3 = *(const v8h*)(Ps + (size_t)wp3 * 192 + c83 * 8);
  v8h p4;
  if (tid < 128) p4 = *(const v8h*)(Ps + (size_t)wp4 * 192 + c84 * 8);

  for (int cand = 0; cand < 6; ++cand) {
    *(v8h*)(Bs + (size_t)wp0 * 200 + c80 * 8) = p0;
    *(v8h*)(Bs + (size_t)wp1 * 200 + c81 * 8) = p1;
    *(v8h*)(Bs + (size_t)wp2 * 200 + c82 * 8) = p2;
    *(v8h*)(Bs + (size_t)wp3 * 200 + c83 * 8) = p3;
    if (tid < 128) *(v8h*)(Bs + (size_t)wp4 * 200 + c84 * 8) = p4;
    __syncthreads();   // Bs ready
    if (cand < 5) {    // issue next slice's loads now; HBM latency hides under compute below
      const h16* Pn = P + ((size_t)((cand + 1) * 2 + sw) * IMGS + img) * HW + (size_t)qt * 9216;
      p0 = *(const v8h*)(Pn + (size_t)wp0 * 192 + c80 * 8);
      p1 = *(const v8h*)(Pn + (size_t)wp1 * 192 + c81 * 8);
      p2 = *(const v8h*)(Pn + (size_t)wp2 * 192 + c82 * 8);
      p3 = *(const v8h*)(Pn + (size_t)wp3 * 192 + c83 * 8);
      if (tid < 128) p4 = *(const v8h*)(Pn + (size_t)wp4 * 192 + c84 * 8);
    }
    const h16* g16 = gate + (size_t)(bimg * 6 + cand) * HW;
    const h16* KB = Kall + (size_t)(cand * 2 + sh) * HW;
#pragma unroll
    for (int mi = 0; mi < 3; ++mi) {
      const int m0 = mbase + mi * 16;
      const int ktlo = imax(0, (m0 - 24) >> 5), kthi = imin(5, (m0 + 39) >> 5);
      const int hr0 = m0 + quad * 4;
      float g[3][4];
#pragma unroll
      for (int nt = 0; nt < 3; ++nt)
#pragma unroll
        for (int r = 0; r < 4; ++r)
          g[nt][r] = (float)g16[(size_t)(hr0 + r) * 192 + w0q + nt * 16 + lm];
      v4f C[3];
#pragma unroll
      for (int nt = 0; nt < 3; ++nt) C[nt] = (v4f){0.f, 0.f, 0.f, 0.f};
      for (int kt = ktlo; kt <= kthi; ++kt) {
        const int k0 = kt * 32 + quad * 8;
        v8h a = *(const v8h*)(KB + (size_t)(m0 + lm) * 192 + k0);
#pragma unroll
        for (int nt = 0; nt < 3; ++nt) {
          v8h b = *(const v8h*)(Bs + (size_t)(nt * 16 + lm) * 200 + k0);
          C[nt] = __builtin_amdgcn_mfma_f32_16x16x32_f16(a, b, C[nt], 0, 0, 0);
        }
      }
#pragma unroll
      for (int nt = 0; nt < 3; ++nt)
#pragma unroll
        for (int r = 0; r < 4; ++r)
          acc[mi][nt][r] += g[nt][r] * C[nt][r];
    }
    __syncthreads();   // compute done before next cand's ds_write (single buffer)
  }
  // epilogue: hf fold + fp16 store
  const float hfv = hfp[0];
  const int s = sw * 2 + sh;
  const float f = (s == 0) ? 1.f : hfv;
  h16* Op = sf + ((size_t)img * 4 + s) * HW;
#pragma unroll
  for (int mi = 0; mi < 3; ++mi) {
    const int hr0 = mbase + mi * 16 + quad * 4;
#pragma unroll
    for (int nt = 0; nt < 3; ++nt) {
      const int wc = w0q + nt * 16 + lm;
#pragma unroll
      for (int r = 0; r < 4; ++r)
        Op[(size_t)(hr0 + r) * 192 + wc] = (h16)(f * acc[mi][nt][r]);
    }
  }
}

// ---------------- final 1x1 projection 128 -> 32 (4 px/thread, v4h loads) ----------------
__global__ __launch_bounds__(256) void k_proj(
    const h16* __restrict__ sf, const float* __restrict__ pw,
    const float* __restrict__ pb, float* __restrict__ out)
{
  const int tid = threadIdx.x;
  const int lane = tid & 63;
  const int og = __builtin_amdgcn_readfirstlane(tid >> 6);   // 0..3, wave-uniform scalar
  const int b = blockIdx.x / 144;                             // 144 blocks per image (256 px each)
  const int p = (blockIdx.x - b * 144) * 256 + lane * 4;
  const h16* sfb = sf + (size_t)(b * 128) * HW + p;
  const float* pwb = pw + og * 8 * 128;                       // scalar base
  float acc[8][4];
#pragma unroll
  for (int oo = 0; oo < 8; ++oo)
#pragma unroll
    for (int j = 0; j < 4; ++j) acc[oo][j] = 0.f;
#pragma unroll 4
  for (int ch = 0; ch < 128; ++ch) {
    v4h hv = *(const v4h*)(sfb + (size_t)ch * HW);
    float v[4];
#pragma unroll
    for (int j = 0; j < 4; ++j) v[j] = (float)hv[j];
#pragma unroll
    for (int oo = 0; oo < 8; ++oo) {
      const float w = pwb[oo * 128 + ch];
#pragma unroll
      for (int j = 0; j < 4; ++j) acc[oo][j] = fmaf(w, v[j], acc[oo][j]);
    }
  }
#pragma unroll
  for (int oo = 0; oo < 8; ++oo) {
    const float bb = pb[og * 8 + oo];
    float4 o4;
    o4.x = acc[oo][0] + bb; o4.y = acc[oo][1] + bb;
    o4.z = acc[oo][2] + bb; o4.w = acc[oo][3] + bb;
    *(float4*)(out + (size_t)(b * 32 + og * 8 + oo) * HW + p) = o4;
  }
}

extern "C" void kernel_launch(void* const* d_in, const int* in_sizes, int n_in,
                              void* d_out, int out_size, void* d_ws, size_t ws_size,
                              hipStream_t stream) {
  (void)in_sizes; (void)n_in; (void)out_size; (void)ws_size;
  const float* x    = (const float*)d_in[0];
  const float* gw1  = (const float*)d_in[1];
  const float* gb1  = (const float*)d_in[2];
  const float* gw2  = (const float*)d_in[3];
  const float* gb2  = (const float*)d_in[4];
  const float* s53A = (const float*)d_in[5];
  const float* s53D = (const float*)d_in[6];
  const float* s97A = (const float*)d_in[7];
  const float* s97D = (const float*)d_in[8];
  const float* hfp  = (const float*)d_in[9];
  const float* pw   = (const float*)d_in[10];
  const float* pb   = (const float*)d_in[11];
  float* out = (float*)d_out;

  // workspace (bytes), total 153,649,152 (proven layout):
  //   gate fp16:          0 ..   1,769,472   (4 x 6 x HW)
  //   Kall fp16:  1,769,472 ..   2,654,208   (12 x 192 x 192)
  //   P    fp16:  2,654,208 .. 115,900,416   (12 x 128 x HW)  layout [plane][img][q4][w'48][h192]
  //   sf   fp16: 115,900,416 .. 153,649,152  (128 x 4 x HW)
  h16* gate = (h16*)d_ws;
  h16* Kall = (h16*)((char*)d_ws + 1769472);
  h16* P    = (h16*)((char*)d_ws + 2654208);
  h16* sf   = (h16*)((char*)d_ws + 115900416);

  hipLaunchKernelGGL(k_gate, dim3(576), dim3(256), 0, stream, x, gw1, gb1, gw2, gb2, gate);
  hipLaunchKernelGGL(k_build, dim3(192, 12), dim3(64), 0, stream, Kall, s53A, s53D, s97A, s97D);
  hipLaunchKernelGGL(k_gw, dim3(36, IMGS), dim3(64), 0, stream, x, Kall, P);
  hipLaunchKernelGGL(k_gh2, dim3(16, IMGS), dim3(256), 0, stream, Kall, P, gate, hfp, sf);
  hipLaunchKernelGGL(k_proj, dim3(576), dim3(256), 0, stream, sf, pw, pb, out);
}

// Round 12
// 266.415 us; speedup vs baseline: 1.8449x; 1.0402x over previous
//
#include <hip/hip_runtime.h>
#include <hip/hip_fp16.h>

#define HW 36864      // 192*192
#define IMGS 128      // B*C

typedef _Float16 h16;
typedef _Float16 v8h __attribute__((ext_vector_type(8)));
typedef _Float16 v4h __attribute__((ext_vector_type(4)));
typedef float v4f __attribute__((ext_vector_type(4)));

static __device__ __forceinline__ int imax(int a, int b) { return a > b ? a : b; }
static __device__ __forceinline__ int imin(int a, int b) { return a < b ? a : b; }

__device__ __constant__ float LIFT_C[6] = {
  -0.5f, 0.25f,                                            // bior53
  -1.586134342f, -0.05298011854f, 0.8829110762f, 0.4435068522f  // bior97
};
__device__ __constant__ int FIR_L[4]   = {8, 12, 12, 30};
__device__ __constant__ int FIR_PA[4]  = {2, 4, 4, 13};
__device__ __constant__ int FIR_OFF[4] = {0, 8, 20, 32};

// raw (unnormalized) FIR lowpass filters concatenated: db4(8) db6(12) sym6(12) coif5(30)
__device__ constexpr float FIRC[62] = {
  -0.0105974017850021f, 0.0328830116668852f, 0.0308413818355607f, -0.1870348117188811f,
  -0.0279837694169839f, 0.6308807679295904f, 0.7148465705529155f, 0.2303778133088964f,
  0.00107730108499558f, -0.00477725751101065f, -0.0005538422009938f, 0.03158203931748603f,
  0.02752286553030533f, -0.0975016055873225f, -0.12976686756709563f, 0.22626469396544f,
  0.3152503517092432f, -0.7511339080210959f, 0.4946238903984534f, 0.1115407433501095f,
  -0.007800708325034148f, 0.001767711864242804f, 0.04472490177066578f, -0.02106029251230056f,
  -0.0726375227866f, 0.3379294217282401f, 0.787641141030194f, 0.4910559419267466f,
  -0.048311742585632f, -0.1179901111484105f, 0.00349071208421747f, 0.01540410932702737f,
  -3.459977283621256e-05f, -7.098330313814114e-05f, 0.0004662169601128863f, 0.001117518770890601f,
  -0.002574517688750223f, -0.00900797613666158f, 0.015880544863615904f, 0.03455502757306163f,
  -0.08230192710688598f, -0.07179982161931202f, 0.42848347637761874f, 0.7937772226256206f,
  0.4051769024096169f, -0.06112339000267287f, -0.06577191128185562f, 0.023452696141836267f,
  0.007782596427325418f, -0.003793512864491014f, -0.0002606761356811993f, 0.000107502882505652f,
  1.10319778524429e-05f, -5.520763127949e-06f, -1.0682196848076e-06f, 5.236425333584e-07f,
  1.125098976034e-07f, -5.417490769329e-08f, -8.8631e-09f, 4.2921e-09f, 6.7e-10f, -3.2e-10f,
};

// ---------------- gate: 1x1 conv -> relu -> 1x1 conv -> softmax -> renorm (fp16 out) ----------------
__global__ __launch_bounds__(256) void k_gate(
    const float* __restrict__ x, const float* __restrict__ w1, const float* __restrict__ b1,
    const float* __restrict__ w2, const float* __restrict__ b2, h16* __restrict__ gate)
{
  __shared__ float w1s[256], b1s[8], w2s[48], b2s[6];
  int tid = threadIdx.x;
  w1s[tid] = w1[tid];
  if (tid < 8)  b1s[tid] = b1[tid];
  if (tid < 48) w2s[tid] = w2[tid];
  if (tid < 6)  b2s[tid] = b2[tid];
  __syncthreads();
  int px = blockIdx.x * 256 + tid;        // exactly 4*HW threads
  int b = px / HW, p = px - b * HW;
  const float* xb = x + (size_t)b * 32 * HW + p;
  float xv[32];
#pragma unroll
  for (int c = 0; c < 32; ++c) xv[c] = xb[(size_t)c * HW];
  float hb[8];
#pragma unroll
  for (int j = 0; j < 8; ++j) {
    float s = b1s[j];
#pragma unroll
    for (int c = 0; c < 32; ++c) s += w1s[j * 32 + c] * xv[c];
    hb[j] = fmaxf(s, 0.f);
  }
  float e[6], mx = -1e30f;
#pragma unroll
  for (int k = 0; k < 6; ++k) {
    float s = b2s[k];
#pragma unroll
    for (int j = 0; j < 8; ++j) s += w2s[k * 8 + j] * hb[j];
    e[k] = s; mx = fmaxf(mx, s);
  }
  float se = 0.f;
#pragma unroll
  for (int k = 0; k < 6; ++k) { e[k] = expf(e[k] - mx); se += e[k]; }
  float inv = 1.f / se, s2 = 0.f;
#pragma unroll
  for (int k = 0; k < 6; ++k) { e[k] *= inv; s2 += e[k]; }
  float inv2 = 1.f / (s2 + 1e-12f);
  h16* gp = gate + (size_t)b * 6 * HW + p;
#pragma unroll
  for (int k = 0; k < 6; ++k) gp[(size_t)k * HW] = (h16)(e[k] * inv2);
}

// ---------------- build the 12 operator matrices (fp16, 192x192 row-major [out][in]) ----------------
__global__ __launch_bounds__(64) void k_build(
    h16* __restrict__ Kall, const float* __restrict__ s53A, const float* __restrict__ s53D,
    const float* __restrict__ s97A, const float* __restrict__ s97D)
{
  const int col = blockIdx.x;      // 0..191 (input index)
  const int mat = blockIdx.y;      // 0..11
  const int cand = mat >> 1, side = mat & 1;
  const int tid = threadIdx.x;
  h16* out = Kall + (size_t)mat * HW;
  if (cand < 4) {
    const int Lf = FIR_L[cand], PA = FIR_PA[cand], OFF = FIR_OFF[cand];
    float ss = 0.f;
    for (int j = 0; j < Lf; ++j) ss += FIRC[OFF + j] * FIRC[OFF + j];
    const float invn = 1.f / (sqrtf(ss) + 1e-12f);
    for (int i = tid; i < 192; i += 64) {
      const int d = (i < 96) ? 1 : 2;
      const int q0 = i - d;
      const int i0 = imax(q0, 0), i1 = imin(q0 + 1, 189);
      const float tt = (float)d - (float)(2 * i + 1) * (1.f / 192.f);
      float c0 = 0.f, c1 = 0.f;
      for (int j = 0; j < Lf; ++j) {
        float fj = side ? (((j & 1) ? -1.f : 1.f) * FIRC[OFF + Lf - 1 - j]) : FIRC[OFF + j];
        fj *= invn;
        int r0 = i0 + j - PA; r0 = r0 < 0 ? -r0 : (r0 > 191 ? 382 - r0 : r0);
        int r1 = i1 + j - PA; r1 = r1 < 0 ? -r1 : (r1 > 191 ? 382 - r1 : r1);
        if (r0 == col) c0 += fj;
        if (r1 == col) c1 += fj;
      }
      out[(size_t)i * 192 + col] = (h16)((1.f - tt) * c0 + tt * c1);
    }
  } else {
    __shared__ float yb[192];
    __shared__ float sb[96];
    yb[tid] = 0.f; yb[tid + 64] = 0.f; yb[tid + 128] = 0.f;
    __syncthreads();
    if (tid == 0) yb[col] = 1.f;
    __syncthreads();
    const int c97 = (cand == 5);
    const int base = c97 ? 2 : 0, ns = c97 ? 4 : 2;
    for (int s = 0; s < ns; ++s) {
      const float cf = LIFT_C[base + s] * 0.5f;
      for (int j = tid; j < 96; j += 64) {
        int jm = (j == 0) ? 1 : j - 1, jp = (j == 95) ? 94 : j + 1;
        if ((s & 1) == 0) yb[2 * j + 1] += cf * (yb[2 * jm] + yb[2 * jp]);
        else              yb[2 * j]     += cf * (yb[2 * jm + 1] + yb[2 * jp + 1]);
      }
      __syncthreads();
    }
    const float sA = c97 ? s97A[0] : s53A[0];
    const float sD = c97 ? s97D[0] : s53D[0];
    for (int u = tid; u < 96; u += 64)
      sb[u] = side ? sD * yb[2 * u + 1] : sA * yb[2 * u];
    __syncthreads();
    for (int i = tid; i < 192; i += 64) {
      const int u0 = (i >> 1) + (i & 1) - 1;
      const float tt = (i & 1) ? 0.25f : 0.75f;
      const int a0 = imax(u0, 0), a1 = imin(u0 + 1, 95);
      out[(size_t)i * 192 + col] = (h16)((1.f - tt) * sb[a0] + tt * sb[a1]);
    }
  }
}

// ---------------- pass W (R11-proven, byte-identical) ----------------
// (12 mt x 3 hc, 128 img) = 4608 single-wave blocks. Register-batched b[4][3], 12-plane loop.
__global__ __launch_bounds__(64) void k_gw(
    const float* __restrict__ x, const h16* __restrict__ Kall, h16* __restrict__ P)
{
  const int bx = blockIdx.x;
  const int mt = bx % 12, hc = bx / 12;          // w'-tile, h-chunk
  const int img = blockIdx.y;
  const int lane = threadIdx.x;
  const int lm = lane & 15, quad = lane >> 4;
  const int m0 = mt * 16;                        // w' tile base
  int ktr = (m0 - 24) >> 5; ktr = ktr < 0 ? 0 : (ktr > 3 ? 3 : ktr);   // 3-slot band window
  const int q = mt / 3;                          // output quarter (m0 = 16*mt stays within q)
  const int wqb = m0 - q * 48;                   // w' base within quarter
  const float* xi = x + (size_t)img * HW;

  v8h b[4][3];
#pragma unroll
  for (int j = 0; j < 4; ++j)
#pragma unroll
    for (int kt = 0; kt < 3; ++kt) {
      const float* xr = xi + (size_t)(hc * 64 + j * 16 + lm) * 192 + (ktr + kt) * 32 + quad * 8;
      float4 u0 = *(const float4*)xr;
      float4 u1 = *(const float4*)(xr + 4);
      v8h t;
      t[0] = (h16)u0.x; t[1] = (h16)u0.y; t[2] = (h16)u0.z; t[3] = (h16)u0.w;
      t[4] = (h16)u1.x; t[5] = (h16)u1.y; t[6] = (h16)u1.z; t[7] = (h16)u1.w;
      b[j][kt] = t;
    }
#pragma unroll 2
  for (int plane = 0; plane < 12; ++plane) {
    const h16* KW = Kall + (size_t)plane * HW + (size_t)(m0 + lm) * 192 + ktr * 32 + quad * 8;
    v8h a0 = *(const v8h*)(KW);
    v8h a1 = *(const v8h*)(KW + 32);
    v8h a2 = *(const v8h*)(KW + 64);
    v4f C[4];
#pragma unroll
    for (int j = 0; j < 4; ++j) C[j] = (v4f){0.f, 0.f, 0.f, 0.f};
#pragma unroll
    for (int j = 0; j < 4; ++j) {
      C[j] = __builtin_amdgcn_mfma_f32_16x16x32_f16(a0, b[j][0], C[j], 0, 0, 0);
      C[j] = __builtin_amdgcn_mfma_f32_16x16x32_f16(a1, b[j][1], C[j], 0, 0, 0);
      C[j] = __builtin_amdgcn_mfma_f32_16x16x32_f16(a2, b[j][2], C[j], 0, 0, 0);
    }
    h16* Pp = P + ((size_t)plane * IMGS + img) * HW + (size_t)q * 9216;
#pragma unroll
    for (int j = 0; j < 4; ++j)
#pragma unroll
      for (int r = 0; r < 4; ++r)
        Pp[(size_t)(wqb + quad * 4 + r) * 192 + hc * 64 + j * 16 + lm] = (h16)C[j][r];
  }
}

// ---------------- pass H + gated combine ----------------
// R11 structure; ONE change: the inner kt loop had DYNAMIC bounds (ktlo..kthi), which blocks
// unrolling -> each kt serializes {a-load ~300cy -> ds_reads -> MFMA} (the R3 disease, fixed
// in k_gw since R4 but never re-applied here after the R4 revert). Now: fixed 3-slot clamped
// window (kt0 = clamp((m0-24)>>5,0,3); slots kt0..kt0+2 cover [m0-24,m0+39]; band is exactly
// zero outside -- harness-proven in R4/R7/R8), fully unrolled -> all loads issue up front.
__global__ __launch_bounds__(256, 2) void k_gh2(
    const h16* __restrict__ Kall, const h16* __restrict__ P, const h16* __restrict__ gate,
    const float* __restrict__ hfp, h16* __restrict__ sf)
{
  __shared__ h16 Bs[48 * 200];
  const int bx = blockIdx.x;
  const int sw = bx & 1, qt = (bx >> 1) & 3, mh = bx >> 3;   // mh 0..1: m-half
  const int img = blockIdx.y;
  const int bimg = img >> 5;
  const int tid = threadIdx.x;
  const int lane = tid & 63, wv = tid >> 6;
  const int lm = lane & 15, quad = lane >> 4;
  const int sh = wv & 1, w4h = wv >> 1;          // 4 waves: sh side x m-quarter-within-half
  const int w0q = qt * 48;
  const int mbase = mh * 96 + w4h * 48;          // this wave's 48-row m block

  // staging: 1152 v8h items over 256 threads (4.5/thread); item -> (wp 0..47, c8 0..23)
  const int wp0 = tid / 24,           c80 = tid - wp0 * 24;
  const int it1 = tid + 256;  const int wp1 = it1 / 24, c81 = it1 - wp1 * 24;
  const int it2 = tid + 512;  const int wp2 = it2 / 24, c82 = it2 - wp2 * 24;
  const int it3 = tid + 768;  const int wp3 = it3 / 24, c83 = it3 - wp3 * 24;
  const int it4 = tid + 1024; const int wp4 = it4 / 24, c84 = it4 - wp4 * 24;  // tid<128 only

  v4f acc[3][3];
#pragma unroll
  for (int mi = 0; mi < 3; ++mi)
#pragma unroll
    for (int nt = 0; nt < 3; ++nt) acc[mi][nt] = (v4f){0.f, 0.f, 0.f, 0.f};

  const h16* Ps = P + ((size_t)sw * IMGS + img) * HW + (size_t)qt * 9216;
  v8h p0 = *(const v8h*)(Ps + (size_t)wp0 * 192 + c80 * 8);
  v8h p1 = *(const v8h*)(Ps + (size_t)wp1 * 192 + c81 * 8);
  v8h p2 = *(const v8h*)(Ps + (size_t)wp2 * 192 + c82 * 8);
  v8h p3 = *(const v8h*)(Ps + (size_t)wp3 * 192 + c83 * 8);
  v8h p4;
  if (tid < 128) p4 = *(const v8h*)(Ps + (size_t)wp4 * 192 + c84 * 8);

  for (int cand = 0; cand < 6; ++cand) {
    *(v8h*)(Bs + (size_t)wp0 * 200 + c80 * 8) = p0;
    *(v8h*)(Bs + (size_t)wp1 * 200 + c81 * 8) = p1;
    *(v8h*)(Bs + (size_t)wp2 * 200 + c82 * 8) = p2;
    *(v8h*)(Bs + (size_t)wp3 * 200 + c83 * 8) = p3;
    if (tid < 128) *(v8h*)(Bs + (size_t)wp4 * 200 + c84 * 8) = p4;
    __syncthreads();   // Bs ready
    if (cand < 5) {    // issue next slice's loads now; HBM latency hides under compute below
      const h16* Pn = P + ((size_t)((cand + 1) * 2 + sw) * IMGS + img) * HW + (size_t)qt * 9216;
      p0 = *(const v8h*)(Pn + (size_t)wp0 * 192 + c80 * 8);
      p1 = *(const v8h*)(Pn + (size_t)wp1 * 192 + c81 * 8);
      p2 = *(const v8h*)(Pn + (size_t)wp2 * 192 + c82 * 8);
      p3 = *(const v8h*)(Pn + (size_t)wp3 * 192 + c83 * 8);
      if (tid < 128) p4 = *(const v8h*)(Pn + (size_t)wp4 * 192 + c84 * 8);
    }
    const h16* g16 = gate + (size_t)(bimg * 6 + cand) * HW;
    const h16* KB = Kall + (size_t)(cand * 2 + sh) * HW;
#pragma unroll
    for (int mi = 0; mi < 3; ++mi) {
      const int m0 = mbase + mi * 16;
      int kt0 = (m0 - 24) >> 5; kt0 = kt0 < 0 ? 0 : (kt0 > 3 ? 3 : kt0);  // fixed 3-slot window
      const int hr0 = m0 + quad * 4;
      float g[3][4];
#pragma unroll
      for (int nt = 0; nt < 3; ++nt)
#pragma unroll
        for (int r = 0; r < 4; ++r)
          g[nt][r] = (float)g16[(size_t)(hr0 + r) * 192 + w0q + nt * 16 + lm];
      v4f C[3];
#pragma unroll
      for (int nt = 0; nt < 3; ++nt) C[nt] = (v4f){0.f, 0.f, 0.f, 0.f};
#pragma unroll
      for (int kt = 0; kt < 3; ++kt) {
        const int k0 = (kt0 + kt) * 32 + quad * 8;
        v8h a = *(const v8h*)(KB + (size_t)(m0 + lm) * 192 + k0);
#pragma unroll
        for (int nt = 0; nt < 3; ++nt) {
          v8h b = *(const v8h*)(Bs + (size_t)(nt * 16 + lm) * 200 + k0);
          C[nt] = __builtin_amdgcn_mfma_f32_16x16x32_f16(a, b, C[nt], 0, 0, 0);
        }
      }
#pragma unroll
      for (int nt = 0; nt < 3; ++nt)
#pragma unroll
        for (int r = 0; r < 4; ++r)
          acc[mi][nt][r] += g[nt][r] * C[nt][r];
    }
    __syncthreads();   // compute done before next cand's ds_write (single buffer)
  }
  // epilogue: hf fold + fp16 store
  const float hfv = hfp[0];
  const int s = sw * 2 + sh;
  const float f = (s == 0) ? 1.f : hfv;
  h16* Op = sf + ((size_t)img * 4 + s) * HW;
#pragma unroll
  for (int mi = 0; mi < 3; ++mi) {
    const int hr0 = mbase + mi * 16 + quad * 4;
#pragma unroll
    for (int nt = 0; nt < 3; ++nt) {
      const int wc = w0q + nt * 16 + lm;
#pragma unroll
      for (int r = 0; r < 4; ++r)
        Op[(size_t)(hr0 + r) * 192 + wc] = (h16)(f * acc[mi][nt][r]);
    }
  }
}

// ---------------- final 1x1 projection 128 -> 32 (4 px/thread, v4h loads) ----------------
__global__ __launch_bounds__(256) void k_proj(
    const h16* __restrict__ sf, const float* __restrict__ pw,
    const float* __restrict__ pb, float* __restrict__ out)
{
  const int tid = threadIdx.x;
  const int lane = tid & 63;
  const int og = __builtin_amdgcn_readfirstlane(tid >> 6);   // 0..3, wave-uniform scalar
  const int b = blockIdx.x / 144;                             // 144 blocks per image (256 px each)
  const int p = (blockIdx.x - b * 144) * 256 + lane * 4;
  const h16* sfb = sf + (size_t)(b * 128) * HW + p;
  const float* pwb = pw + og * 8 * 128;                       // scalar base
  float acc[8][4];
#pragma unroll
  for (int oo = 0; oo < 8; ++oo)
#pragma unroll
    for (int j = 0; j < 4; ++j) acc[oo][j] = 0.f;
#pragma unroll 4
  for (int ch = 0; ch < 128; ++ch) {
    v4h hv = *(const v4h*)(sfb + (size_t)ch * HW);
    float v[4];
#pragma unroll
    for (int j = 0; j < 4; ++j) v[j] = (float)hv[j];
#pragma unroll
    for (int oo = 0; oo < 8; ++oo) {
      const float w = pwb[oo * 128 + ch];
#pragma unroll
      for (int j = 0; j < 4; ++j) acc[oo][j] = fmaf(w, v[j], acc[oo][j]);
    }
  }
#pragma unroll
  for (int oo = 0; oo < 8; ++oo) {
    const float bb = pb[og * 8 + oo];
    float4 o4;
    o4.x = acc[oo][0] + bb; o4.y = acc[oo][1] + bb;
    o4.z = acc[oo][2] + bb; o4.w = acc[oo][3] + bb;
    *(float4*)(out + (size_t)(b * 32 + og * 8 + oo) * HW + p) = o4;
  }
}

extern "C" void kernel_launch(void* const* d_in, const int* in_sizes, int n_in,
                              void* d_out, int out_size, void* d_ws, size_t ws_size,
                              hipStream_t stream) {
  (void)in_sizes; (void)n_in; (void)out_size; (void)ws_size;
  const float* x    = (const float*)d_in[0];
  const float* gw1  = (const float*)d_in[1];
  const float* gb1  = (const float*)d_in[2];
  const float* gw2  = (const float*)d_in[3];
  const float* gb2  = (const float*)d_in[4];
  const float* s53A = (const float*)d_in[5];
  const float* s53D = (const float*)d_in[6];
  const float* s97A = (const float*)d_in[7];
  const float* s97D = (const float*)d_in[8];
  const float* hfp  = (const float*)d_in[9];
  const float* pw   = (const float*)d_in[10];
  const float* pb   = (const float*)d_in[11];
  float* out = (float*)d_out;

  // workspace (bytes), total 153,649,152 (proven layout):
  //   gate fp16:          0 ..   1,769,472   (4 x 6 x HW)
  //   Kall fp16:  1,769,472 ..   2,654,208   (12 x 192 x 192)
  //   P    fp16:  2,654,208 .. 115,900,416   (12 x 128 x HW)  layout [plane][img][q4][w'48][h192]
  //   sf   fp16: 115,900,416 .. 153,649,152  (128 x 4 x HW)
  h16* gate = (h16*)d_ws;
  h16* Kall = (h16*)((char*)d_ws + 1769472);
  h16* P    = (h16*)((char*)d_ws + 2654208);
  h16* sf   = (h16*)((char*)d_ws + 115900416);

  hipLaunchKernelGGL(k_gate, dim3(576), dim3(256), 0, stream, x, gw1, gb1, gw2, gb2, gate);
  hipLaunchKernelGGL(k_build, dim3(192, 12), dim3(64), 0, stream, Kall, s53A, s53D, s97A, s97D);
  hipLaunchKernelGGL(k_gw, dim3(36, IMGS), dim3(64), 0, stream, x, Kall, P);
  hipLaunchKernelGGL(k_gh2, dim3(16, IMGS), dim3(256), 0, stream, Kall, P, gate, hfp, sf);
  hipLaunchKernelGGL(k_proj, dim3(576), dim3(256), 0, stream, sf, pw, pb, out);
}